// Round 13
// baseline (132.045 us; speedup 1.0000x reference)
//
#include <hip/hip_runtime.h>

#define D 1024
#define B 32
#define NI 1024
#define PP 1000
#define R 3
#define SPLITS 8        // split-K factor for weight GEMMs (K chunk = 128)
#define VS 8            // p-split factor for v_agg (128 padded p each)
#define BK 32
#define KT (D / SPLITS / BK)   // k-tiles per split
#define PAD 34          // row pad (floats): b64 reads land 2-way-conflict only (free)

typedef float f32x4_t __attribute__((ext_vector_type(4)));

__device__ __forceinline__ void nt_store4v(float* p, f32x4_t x) {
    __builtin_nontemporal_store(x, (f32x4_t*)p);
}

__device__ __forceinline__ float wred(float x) {
    #pragma unroll
    for (int off = 32; off; off >>= 1) x += __shfl_xor(x, off, 64);
    return x;
}
__device__ __forceinline__ float wmax(float x) {
    #pragma unroll
    for (int off = 32; off; off >>= 1) x = fmaxf(x, __shfl_xor(x, off, 64));
    return x;
}

// ---------------------------------------------------------------------------
// Tiled GEMM core: C[m, b] = sum_k A[m, k] * X[b, k], K-range [kc0, kc0+D/SPLITS)
// X rows may be a sum of NXS partial buffers; optional bias added to X rows.
// ---------------------------------------------------------------------------
template<int NXS, bool XB = false>
__device__ __forceinline__ void gemm_core(
        const float* __restrict__ A, int mbase, int Mrows,
        const float* __restrict__ Xb, int xrstride, size_t xss,
        int kc0, float acc[4][4], const float* __restrict__ xbias = nullptr) {
    __shared__ float Ws[128][PAD];
    __shared__ float Xs[32][PAD];
    const int t = threadIdx.x;
    const int ty = t >> 3, tx = t & 7;
    const int m0 = 4 * ty, b0 = 4 * tx;
    const int lrow = t >> 3, lq = t & 7;

    #pragma unroll
    for (int i = 0; i < 4; ++i)
        #pragma unroll
        for (int j = 0; j < 4; ++j) acc[i][j] = 0.f;

    for (int kt = 0; kt < KT; ++kt) {
        const int kc = kc0 + kt * BK;
        #pragma unroll
        for (int rr = 0; rr < 4; ++rr) {
            const int row = lrow + 32 * rr;
            float4 v = make_float4(0.f, 0.f, 0.f, 0.f);
            if (mbase + row < Mrows)
                v = *(const float4*)(A + (size_t)(mbase + row) * D + kc + 4 * lq);
            *(float2*)&Ws[row][4 * lq]     = make_float2(v.x, v.y);
            *(float2*)&Ws[row][4 * lq + 2] = make_float2(v.z, v.w);
        }
        {
            const float* xp = Xb + (size_t)lrow * xrstride + kc + 4 * lq;
            float4 v = *(const float4*)xp;
            #pragma unroll
            for (int s = 1; s < NXS; ++s) {
                float4 w = *(const float4*)(xp + (size_t)s * xss);
                v.x += w.x; v.y += w.y; v.z += w.z; v.w += w.w;
            }
            if constexpr (XB) {
                float4 bb = *(const float4*)(xbias + kc + 4 * lq);
                v.x += bb.x; v.y += bb.y; v.z += bb.z; v.w += bb.w;
            }
            *(float2*)&Xs[lrow][4 * lq]     = make_float2(v.x, v.y);
            *(float2*)&Xs[lrow][4 * lq + 2] = make_float2(v.z, v.w);
        }
        __syncthreads();
        #pragma unroll
        for (int kp = 0; kp < 16; ++kp) {
            float2 wv[4], xv[4];
            #pragma unroll
            for (int i = 0; i < 4; ++i) wv[i] = *(const float2*)&Ws[m0 + i][2 * kp];
            #pragma unroll
            for (int j = 0; j < 4; ++j) xv[j] = *(const float2*)&Xs[b0 + j][2 * kp];
            #pragma unroll
            for (int i = 0; i < 4; ++i)
                #pragma unroll
                for (int j = 0; j < 4; ++j) {
                    acc[i][j] += wv[i].x * xv[j].x;
                    acc[i][j] += wv[i].y * xv[j].y;
                }
        }
        __syncthreads();
    }
}

// K1q: three X=fc GEMMs in one launch. mb<24: Wagg->qallp; 24..31: Wq->qkvp
// kind 0; 32..39: Wc->avhp (Wc·vhat partials, chain-independent).
__global__ __launch_bounds__(256) void gemm_k1q(const float* __restrict__ Wagg,
        const float* __restrict__ Wq, const float* __restrict__ Wc,
        const float* __restrict__ fc, float* __restrict__ qallp,
        float* __restrict__ qkvp, float* __restrict__ avhp) {
    const int mb = blockIdx.x, s = blockIdx.y;
    const int t = threadIdx.x, ty = t >> 3, tx = t & 7;
    float acc[4][4];
    if (mb < 24) {
        const int mbase = mb * 128;
        gemm_core<1>(Wagg, mbase, R * D, fc, D, 0, s * 128, acc);
        const int m = mbase + 4 * ty;
        #pragma unroll
        for (int j = 0; j < 4; ++j) {
            float* cp = qallp + ((size_t)(s * B) + 4 * tx + j) * (R * D) + m;
            *(float4*)cp = make_float4(acc[0][j], acc[1][j], acc[2][j], acc[3][j]);
        }
    } else if (mb < 32) {
        const int mbase = (mb - 24) * 128;
        gemm_core<1>(Wq, mbase, D, fc, D, 0, s * 128, acc);
        const int m = mbase + 4 * ty;
        #pragma unroll
        for (int j = 0; j < 4; ++j) {
            float* cp = qkvp + ((size_t)((s * R + 0) * B) + 4 * tx + j) * D + m;
            *(float4*)cp = make_float4(acc[0][j], acc[1][j], acc[2][j], acc[3][j]);
        }
    } else {
        const int mbase = (mb - 32) * 128;
        gemm_core<1>(Wc, mbase, D, fc, D, 0, s * 128, acc);
        const int m = mbase + 4 * ty;
        #pragma unroll
        for (int j = 0; j < 4; ++j) {
            float* cp = avhp + ((size_t)(s * B) + 4 * tx + j) * D + m;
            *(float4*)cp = make_float4(acc[0][j], acc[1][j], acc[2][j], acc[3][j]);
        }
    }
}

// K2: score partials. Cp layout: [s][r][b][1024] (only m<1000 valid)
__global__ __launch_bounds__(256) void gemm_k2(const float* __restrict__ pool,
        const float* __restrict__ qallp, float* __restrict__ Cp) {
    const int mb = blockIdx.x, s = blockIdx.y, r = blockIdx.z;
    const int mbase = mb * 128;
    float acc[4][4];
    gemm_core<SPLITS>(pool, mbase, PP, qallp + r * D, R * D, (size_t)B * R * D,
                      s * 128, acc);
    const int t = threadIdx.x, ty = t >> 3, tx = t & 7;
    const int m = mbase + 4 * ty;
    if (m >= PP) return;
    #pragma unroll
    for (int j = 0; j < 4; ++j) {
        float* cp = Cp + ((size_t)((s * R + r) * B) + 4 * tx + j) * D + m;
        *(float4*)cp = make_float4(acc[0][j], acc[1][j], acc[2][j], acc[3][j]);
    }
}

// K5kv: k/v partials. z: 0->Wk (kind 1), 1->Wv (kind 2). X = sum of VS vagg partials.
__global__ __launch_bounds__(256) void gemm_k5kv(const float* __restrict__ Wk,
        const float* __restrict__ Wv, const float* __restrict__ vaggp,
        float* __restrict__ Cp) {
    const int mb = blockIdx.x, s = blockIdx.y, z = blockIdx.z;
    const int mbase = mb * 128;
    float acc[4][4];
    gemm_core<VS>((z == 0) ? Wk : Wv, mbase, D, vaggp, D, (size_t)B * D,
                  s * 128, acc);
    const int t = threadIdx.x, ty = t >> 3, tx = t & 7;
    const int m = mbase + 4 * ty;
    #pragma unroll
    for (int j = 0; j < 4; ++j) {
        float* cp = Cp + ((size_t)((s * R + z + 1) * B) + 4 * tx + j) * D + m;
        *(float4*)cp = make_float4(acc[0][j], acc[1][j], acc[2][j], acc[3][j]);
    }
}

// K7v: Wcv partials = Wc · v, where v[b] = sum_s v-partials + bv (bias folded
// into X staging). Cp layout: [s][b][1024]
__global__ __launch_bounds__(256) void gemm_k7v(const float* __restrict__ Wc,
        const float* __restrict__ qkvp, const float* __restrict__ bv,
        float* __restrict__ Cp) {
    const int mb = blockIdx.x, s = blockIdx.y;
    const int mbase = mb * 128;
    float acc[4][4];
    gemm_core<SPLITS, true>(Wc, mbase, D, qkvp + (size_t)2 * B * D, D,
                            (size_t)R * B * D, s * 128, acc, bv);
    const int t = threadIdx.x, ty = t >> 3, tx = t & 7;
    const int m = mbase + 4 * ty;
    #pragma unroll
    for (int j = 0; j < 4; ++j) {
        float* cp = Cp + ((size_t)(s * B) + 4 * tx + j) * D + m;
        *(float4*)cp = make_float4(acc[0][j], acc[1][j], acc[2][j], acc[3][j]);
    }
}

// K3w: per b: for r=0..2 softmax over p of summed score partials; accumulate
// wbar[b][p] = (1/3) sum_r softmax_r[p], zero-padded to 1024.
__global__ __launch_bounds__(256) void k3_wbar(const float* __restrict__ scp,
        float* __restrict__ wbar) {
    const int b = blockIdx.x;
    const int t = threadIdx.x, w = t >> 6, lane = t & 63;
    __shared__ float red[8];
    float wb[4] = {0.f, 0.f, 0.f, 0.f};
    for (int r = 0; r < R; ++r) {
        float v[4];
        float mx = -1e30f;
        #pragma unroll
        for (int i = 0; i < 4; ++i) {
            const int p = t + 256 * i;
            float x = -1e30f;
            if (p < PP) {
                x = 0.f;
                #pragma unroll
                for (int s = 0; s < SPLITS; ++s)
                    x += scp[((size_t)((s * R + r) * B) + b) * D + p];
                x *= 0.03125f;
            }
            v[i] = x;
            mx = fmaxf(mx, x);
        }
        mx = wmax(mx);
        if (lane == 0) red[w] = mx;
        __syncthreads();
        mx = fmaxf(fmaxf(red[0], red[1]), fmaxf(red[2], red[3]));
        float e[4], sum = 0.f;
        #pragma unroll
        for (int i = 0; i < 4; ++i) {
            const int p = t + 256 * i;
            e[i] = (p < PP) ? __expf(v[i] - mx) : 0.f;
            sum += e[i];
        }
        sum = wred(sum);
        if (lane == 0) red[4 + w] = sum;
        __syncthreads();
        const float inv = 1.f / (red[4] + red[5] + red[6] + red[7]);
        #pragma unroll
        for (int i = 0; i < 4; ++i) wb[i] += e[i] * inv;
        __syncthreads();
    }
    #pragma unroll
    for (int i = 0; i < 4; ++i) {
        const int p = t + 256 * i;
        wbar[(size_t)b * 1024 + p] = wb[i] * (1.f / 3.f);
    }
}

// K4: v_agg partials as micro-tiled GEMM over p.
__global__ __launch_bounds__(256) void k4_vagg(const float* __restrict__ wbar,
        const float* __restrict__ pool, float* __restrict__ vaggp) {
    const int db = blockIdx.x, ps = blockIdx.y;
    __shared__ float Ps[32][132];
    __shared__ float Wbt[32][36];
    const int t = threadIdx.x;
    const int ty = t >> 3, tx = t & 7;
    float acc[4][4];
    #pragma unroll
    for (int i = 0; i < 4; ++i)
        #pragma unroll
        for (int j = 0; j < 4; ++j) acc[i][j] = 0.f;

    for (int pt = 0; pt < 4; ++pt) {
        const int p0 = ps * 128 + pt * 32;
        {
            const int prow = t >> 5, qc = t & 31;
            #pragma unroll
            for (int rr = 0; rr < 4; ++rr) {
                const int pr = prow + 8 * rr;
                float4 v = make_float4(0.f, 0.f, 0.f, 0.f);
                if (p0 + pr < PP)
                    v = *(const float4*)(pool + (size_t)(p0 + pr) * D + db * 128 + 4 * qc);
                *(float4*)&Ps[pr][4 * qc] = v;
            }
        }
        {
            const int bb = t >> 3, q = t & 7;
            float4 v = *(const float4*)(wbar + (size_t)bb * 1024 + p0 + 4 * q);
            Wbt[4 * q + 0][bb] = v.x; Wbt[4 * q + 1][bb] = v.y;
            Wbt[4 * q + 2][bb] = v.z; Wbt[4 * q + 3][bb] = v.w;
        }
        __syncthreads();
        #pragma unroll
        for (int pg = 0; pg < 8; ++pg) {
            #pragma unroll
            for (int pp = 0; pp < 4; ++pp) {
                const int p = 4 * pg + pp;
                float4 xv = *(const float4*)&Ps[p][4 * ty];
                float4 wv = *(const float4*)&Wbt[p][4 * tx];
                const float xs[4] = {xv.x, xv.y, xv.z, xv.w};
                const float wsv[4] = {wv.x, wv.y, wv.z, wv.w};
                #pragma unroll
                for (int i = 0; i < 4; ++i)
                    #pragma unroll
                    for (int j = 0; j < 4; ++j)
                        acc[i][j] += xs[i] * wsv[j];
            }
        }
        __syncthreads();
    }
    const int dbase = db * 128 + 4 * ty;
    #pragma unroll
    for (int j = 0; j < 4; ++j) {
        float* op = vaggp + ((size_t)ps * B + 4 * tx + j) * D + dbase;
        *(float4*)op = make_float4(acc[0][j], acc[1][j], acc[2][j], acc[3][j]);
    }
}

// K8n: per b: q,k from partials(+bias) -> sig; vdiff = relu(avh - sig*wcv + bc);
// cb = dot(vdiff, Wg2) + bg.  (k6 eliminated via Wc·u = Wc·vhat - sig·Wc·v)
__global__ __launch_bounds__(256) void k8_new(const float* __restrict__ qkvp,
        const float* __restrict__ bq, const float* __restrict__ bk,
        const float* __restrict__ avhp, const float* __restrict__ wcvp,
        const float* __restrict__ bc, const float* __restrict__ Wg,
        const float* __restrict__ bg, float* __restrict__ vdiff,
        float* __restrict__ cb) {
    const int b = blockIdx.x;
    const int t = threadIdx.x, w = t >> 6, lane = t & 63;
    const int d = 4 * t;
    __shared__ float red[4];
    float4 qv = *(const float4*)(bq + d);
    float4 kv = *(const float4*)(bk + d);
    #pragma unroll
    for (int s = 0; s < SPLITS; ++s) {
        float4 a = *(const float4*)(qkvp + ((size_t)((s * R + 0) * B) + b) * D + d);
        float4 c = *(const float4*)(qkvp + ((size_t)((s * R + 1) * B) + b) * D + d);
        qv.x += a.x; qv.y += a.y; qv.z += a.z; qv.w += a.w;
        kv.x += c.x; kv.y += c.y; kv.z += c.z; kv.w += c.w;
    }
    float local = qv.x * kv.x + qv.y * kv.y + qv.z * kv.z + qv.w * kv.w;
    local = wred(local);
    if (lane == 0) red[w] = local;
    __syncthreads();
    const float sim = (red[0] + red[1] + red[2] + red[3]) * 0.03125f;
    const float sig = 1.f / (1.f + __expf(-sim));

    float4 av = make_float4(0.f, 0.f, 0.f, 0.f);
    float4 wc = make_float4(0.f, 0.f, 0.f, 0.f);
    #pragma unroll
    for (int s = 0; s < SPLITS; ++s) {
        float4 a = *(const float4*)(avhp + ((size_t)(s * B) + b) * D + d);
        float4 c = *(const float4*)(wcvp + ((size_t)(s * B) + b) * D + d);
        av.x += a.x; av.y += a.y; av.z += a.z; av.w += a.w;
        wc.x += c.x; wc.y += c.y; wc.z += c.z; wc.w += c.w;
    }
    const float4 bcv = *(const float4*)(bc + d);
    float4 vd;
    vd.x = fmaxf(av.x - sig * wc.x + bcv.x, 0.f);
    vd.y = fmaxf(av.y - sig * wc.y + bcv.y, 0.f);
    vd.z = fmaxf(av.z - sig * wc.z + bcv.z, 0.f);
    vd.w = fmaxf(av.w - sig * wc.w + bcv.w, 0.f);
    *(float4*)(vdiff + (size_t)b * D + d) = vd;

    const float4 g2 = *(const float4*)(Wg + D + d);
    float local2 = vd.x * g2.x + vd.y * g2.y + vd.z * g2.z + vd.w * g2.w;
    local2 = wred(local2);
    __syncthreads();   // everyone done reading red[] for sim
    if (lane == 0) red[w] = local2;
    __syncthreads();
    if (t == 0) cb[b] = red[0] + red[1] + red[2] + red[3] + bg[0];
}

// K9: out[b,n,d] = att + rs * sigmoid(att[b,n,:].Wg1 + cb[b]) * vdiff[b,d]
// asm-volatile pipelined (round-12 best: 75.3us). DO NOT TOUCH.
#define LD16(dst, srcp) \
    asm volatile("global_load_dwordx4 %0, %1, off" : "=v"(dst) : "v"(srcp) : "memory")

__global__ __launch_bounds__(256) void k9_main(const float* __restrict__ att,
        const float* __restrict__ Wg, const float* __restrict__ cb,
        const float* __restrict__ vdiff, const float* __restrict__ rs_p,
        float* __restrict__ out) {
    __shared__ float vds[1024];
    const int t = threadIdx.x;
    const int b = blockIdx.x >> 5;          // 32 blocks per batch, 32 rows/block
    *(float4*)&vds[4 * t] = *(const float4*)(vdiff + (size_t)b * D + 4 * t);
    __syncthreads();
    const int w = t >> 6, lane = t & 63;
    float4 g[4];
    #pragma unroll
    for (int kk = 0; kk < 4; ++kk)
        g[kk] = *(const float4*)(Wg + 4 * lane + 256 * kk);
    const float rsv = rs_p[0];
    const float cbb = cb[b];
    const size_t row0 = (size_t)blockIdx.x * 32 + w * 8;   // 8 rows per wave
    const float* ap = att + row0 * D;
    float* op = out + row0 * D;
    const int co = 4 * lane;

    f32x4_t bufA[8], bufB[8];

#define PAIR_COMPUTE_STORE(BUF, OPB)                                          \
    {                                                                         \
        float acc0 = 0.f, acc1 = 0.f;                                         \
        _Pragma("unroll")                                                     \
        for (int kk = 0; kk < 4; ++kk) {                                      \
            acc0 += BUF[kk][0] * g[kk].x + BUF[kk][1] * g[kk].y +             \
                    BUF[kk][2] * g[kk].z + BUF[kk][3] * g[kk].w;              \
            acc1 += BUF[4 + kk][0] * g[kk].x + BUF[4 + kk][1] * g[kk].y +     \
                    BUF[4 + kk][2] * g[kk].z + BUF[4 + kk][3] * g[kk].w;      \
        }                                                                     \
        _Pragma("unroll")                                                     \
        for (int off = 32; off; off >>= 1) {                                  \
            acc0 += __shfl_xor(acc0, off, 64);                                \
            acc1 += __shfl_xor(acc1, off, 64);                                \
        }                                                                     \
        const float grs0 = rsv / (1.f + __expf(-(acc0 + cbb)));               \
        const float grs1 = rsv / (1.f + __expf(-(acc1 + cbb)));               \
        _Pragma("unroll")                                                     \
        for (int kk = 0; kk < 4; ++kk) {                                      \
            const int col = co + 256 * kk;                                    \
            const float4 vd = *(const float4*)&vds[col];                      \
            f32x4_t o0, o1;                                                   \
            o0[0] = BUF[kk][0] + grs0 * vd.x; o0[1] = BUF[kk][1] + grs0 * vd.y; \
            o0[2] = BUF[kk][2] + grs0 * vd.z; o0[3] = BUF[kk][3] + grs0 * vd.w; \
            o1[0] = BUF[4 + kk][0] + grs1 * vd.x; o1[1] = BUF[4 + kk][1] + grs1 * vd.y; \
            o1[2] = BUF[4 + kk][2] + grs1 * vd.z; o1[3] = BUF[4 + kk][3] + grs1 * vd.w; \
            nt_store4v((OPB) + col, o0);                                      \
            nt_store4v((OPB) + D + col, o1);                                  \
        }                                                                     \
    }

#define ISSUE_PAIR(BUF, ROWOFF)                                               \
    _Pragma("unroll")                                                         \
    for (int q = 0; q < 8; ++q) {                                             \
        const float* _src = ap + (size_t)((ROWOFF) + (q >> 2)) * D + co + 256 * (q & 3); \
        LD16(BUF[q], _src);                                                   \
    }

    ISSUE_PAIR(bufA, 0);
    asm volatile("s_waitcnt vmcnt(0)");
    __builtin_amdgcn_sched_barrier(0);

    ISSUE_PAIR(bufB, 2);
    PAIR_COMPUTE_STORE(bufA, op);

    ISSUE_PAIR(bufA, 4);
    asm volatile("s_waitcnt vmcnt(16)");
    __builtin_amdgcn_sched_barrier(0);
    PAIR_COMPUTE_STORE(bufB, op + 2 * D);

    ISSUE_PAIR(bufB, 6);
    asm volatile("s_waitcnt vmcnt(16)");
    __builtin_amdgcn_sched_barrier(0);
    PAIR_COMPUTE_STORE(bufA, op + 4 * D);

    asm volatile("s_waitcnt vmcnt(8)");
    __builtin_amdgcn_sched_barrier(0);
    PAIR_COMPUTE_STORE(bufB, op + 6 * D);
}

extern "C" void kernel_launch(void* const* d_in, const int* in_sizes, int n_in,
                              void* d_out, int out_size, void* d_ws, size_t ws_size,
                              hipStream_t stream) {
    const float* att  = (const float*)d_in[0];
    const float* fc   = (const float*)d_in[1];
    const float* pool = (const float*)d_in[2];
    const float* Wagg = (const float*)d_in[3];
    const float* Wq   = (const float*)d_in[4];
    const float* bq   = (const float*)d_in[5];
    const float* Wk   = (const float*)d_in[6];
    const float* bk   = (const float*)d_in[7];
    const float* Wv   = (const float*)d_in[8];
    const float* bv   = (const float*)d_in[9];
    const float* Wc   = (const float*)d_in[10];
    const float* bc   = (const float*)d_in[11];
    const float* Wg   = (const float*)d_in[12];
    const float* bg   = (const float*)d_in[13];
    const float* rs   = (const float*)d_in[14];
    float* out = (float*)d_out;

    float* ws = (float*)d_ws;
    float* qallp = ws;                                  // SPLITS*B*R*D
    float* scp   = qallp + (size_t)SPLITS * B * R * D;  // SPLITS*R*B*D
    float* wbar  = scp + (size_t)SPLITS * R * B * D;    // B*1024
    float* vaggp = wbar + (size_t)B * 1024;             // VS*B*D
    float* qkvp  = vaggp + (size_t)VS * B * D;          // SPLITS*R*B*D
    float* avhp  = qkvp + (size_t)SPLITS * R * B * D;   // SPLITS*B*D
    float* wcvp  = avhp + (size_t)SPLITS * B * D;       // SPLITS*B*D
    float* vdiff = wcvp + (size_t)SPLITS * B * D;       // B*D
    float* cbuf  = vdiff + (size_t)B * D;               // B

    gemm_k1q<<<dim3(40, SPLITS), 256, 0, stream>>>(Wagg, Wq, Wc, fc,
                                                   qallp, qkvp, avhp);
    gemm_k2<<<dim3(8, SPLITS, R), 256, 0, stream>>>(pool, qallp, scp);
    k3_wbar<<<B, 256, 0, stream>>>(scp, wbar);
    k4_vagg<<<dim3(8, VS), 256, 0, stream>>>(wbar, pool, vaggp);
    gemm_k5kv<<<dim3(8, SPLITS, 2), 256, 0, stream>>>(Wk, Wv, vaggp, qkvp);
    gemm_k7v<<<dim3(8, SPLITS), 256, 0, stream>>>(Wc, qkvp, bv, wcvp);
    k8_new<<<B, 256, 0, stream>>>(qkvp, bq, bk, avhp, wcvp, bc, Wg, bg,
                                  vdiff, cbuf);
    k9_main<<<B * 32, 256, 0, stream>>>(att, Wg, cbuf, vdiff, rs, out);
}